// Round 1
// baseline (56.341 us; speedup 1.0000x reference)
//
#include <hip/hip_runtime.h>

// 54x54-bit array multiplier over {0,1}-valued float bit-vectors.
// Key insight: the reference's differentiable gate network (XOR=a+b-2ab,
// AND=ab, OR=a+b-ab, ripple-carry adds) is EXACT integer multiplication when
// inputs are exactly 0.0/1.0. So: pack bits -> 64x64->128 multiply -> unpack.
//
// One 64-lane wave per batch row:
//   - lane i (i<54) reads A[row][i], B[row][i]  (coalesced)
//   - __ballot packs each into a wave-uniform uint64
//   - lo = a*b, hi = __umul64hi(a,b)  => 108-bit product
//   - lane i writes out bit i (from lo); lanes 0..43 also write bits 64..107
#define BITS 54
#define OUT_BITS 108

__global__ __launch_bounds__(256) void mult54_kernel(const float* __restrict__ A,
                                                     const float* __restrict__ B,
                                                     float* __restrict__ out,
                                                     int batch) {
    const int gtid = blockIdx.x * blockDim.x + threadIdx.x;
    const int row  = gtid >> 6;          // one wave (64 lanes) per row
    const int lane = threadIdx.x & 63;
    if (row >= batch) return;            // whole waves exit together

    const float* __restrict__ arow = A + (size_t)row * BITS;
    const float* __restrict__ brow = B + (size_t)row * BITS;

    bool abit = false, bbit = false;
    if (lane < BITS) {
        abit = arow[lane] > 0.5f;
        bbit = brow[lane] > 0.5f;
    }
    unsigned long long a = __ballot(abit);   // bit i of mask = lane i's bit -> LSB-first int
    unsigned long long b = __ballot(bbit);

    unsigned long long lo = a * b;
    unsigned long long hi = __umul64hi(a, b);   // bits 64..107 live in hi[0..43]

    float* __restrict__ orow = out + (size_t)row * OUT_BITS;
    orow[lane] = (float)((lo >> lane) & 1ull);
    if (lane < OUT_BITS - 64) {
        orow[64 + lane] = (float)((hi >> lane) & 1ull);
    }
}

extern "C" void kernel_launch(void* const* d_in, const int* in_sizes, int n_in,
                              void* d_out, int out_size, void* d_ws, size_t ws_size,
                              hipStream_t stream) {
    const float* A = (const float*)d_in[0];
    const float* B = (const float*)d_in[1];
    float* out = (float*)d_out;

    const int batch = in_sizes[0] / BITS;      // 8192
    const int threads_total = batch * 64;      // one wave per row
    const int block = 256;
    const int grid = (threads_total + block - 1) / block;

    hipLaunchKernelGGL(mult54_kernel, dim3(grid), dim3(block), 0, stream,
                       A, B, out, batch);
}